// Round 6
// baseline (734.210 us; speedup 1.0000x reference)
//
#include <hip/hip_runtime.h>
#include <hip/hip_fp16.h>

#define N_TOK 131072
#define KCODES 1024
#define DIM 64
#define QUANT_OFF 1
#define PERP_OFF 8388609
#define ENC_OFF ((size_t)8388610)
#define EPS_SUSPECT 4e-3f

typedef __attribute__((ext_vector_type(8))) unsigned short ushort8v;
typedef __attribute__((ext_vector_type(8))) _Float16 half8v;
typedef __attribute__((ext_vector_type(4))) float f32x4;

__device__ __forceinline__ float wave_reduce_sum(float v) {
    #pragma unroll
    for (int o = 32; o > 0; o >>= 1) v += __shfl_xor(v, o, 64);
    return v;
}

// split 8 fp32 -> fp16 hi + fp16 lo (f ~= hi + lo to ~2^-23 rel)
__device__ __forceinline__ void cvt8h(const float4 a, const float4 b,
                                      half8v* h, half8v* l) {
    float f[8] = {a.x, a.y, a.z, a.w, b.x, b.y, b.z, b.w};
    #pragma unroll
    for (int j = 0; j < 8; ++j) {
        _Float16 hh = (_Float16)f[j];
        float fh = (float)hh;
        _Float16 ll = (_Float16)(f[j] - fh);
        (*h)[j] = hh;
        (*l)[j] = ll;
    }
}

// K0: cbuf[j]=0.5*||e_j||^2 (exact fp32, shuffle-tree = r1 order); fp16 split planes; zero dwacc+suspcnt
__global__ void k0_prep(const float* __restrict__ ew, float* __restrict__ cbuf,
                        unsigned short* __restrict__ ewh, unsigned short* __restrict__ ewl,
                        float* __restrict__ dwacc, unsigned* __restrict__ suspcnt) {
    int tid = threadIdx.x;
    int lane = tid & 63;
    int wg = blockIdx.x * 4 + (tid >> 6);   // 128 waves
    int gt = blockIdx.x * 256 + tid;        // 8192 threads
    if (gt == 0) *suspcnt = 0u;
    #pragma unroll
    for (int z = 0; z < 8; ++z) {
        int e = gt * 8 + z;
        float v = ew[e];
        _Float16 hh = (_Float16)v;
        float fh = (float)hh;
        _Float16 ll = (_Float16)(v - fh);
        unsigned short uh, ul;
        __builtin_memcpy(&uh, &hh, 2);
        __builtin_memcpy(&ul, &ll, 2);
        ewh[e] = uh;
        ewl[e] = ul;
        dwacc[e] = 0.0f;
    }
    #pragma unroll
    for (int k = 0; k < 8; ++k) {
        int row = wg * 8 + k;
        float v = ew[row * 64 + lane];
        float s = wave_reduce_sum(v * v);
        if (lane == 0) cbuf[row] = 0.5f * s;
    }
}

// K1: MFMA argmin filter (fp16 4-term) + top-2 tracking + suspect list + encodings zero-fill.
// 1024 blocks x 256 thr; block = 128 tokens (4 waves x 32), codes in 8 chunks of 128.
__global__ __launch_bounds__(256) void k1_argmin(
        const float* __restrict__ x, const unsigned short* __restrict__ ewh,
        const unsigned short* __restrict__ ewl, const float* __restrict__ cbuf,
        float* __restrict__ out, unsigned* __restrict__ idxbuf,
        unsigned* __restrict__ susp, unsigned* __restrict__ suspcnt) {
    __shared__ unsigned short EH[128 * 64];   // fp16 hi, XOR-swizzled rows
    __shared__ unsigned short EL[128 * 64];   // fp16 lo
    __shared__ float scc[128];

    int tid = threadIdx.x;
    int lane = tid & 63;
    int wv = tid >> 6;
    int l15 = lane & 15;
    int l4 = lane >> 4;
    size_t t0 = (size_t)blockIdx.x * 128;
    size_t t0w = t0 + (size_t)wv * 32;

    // A fragments: wave's 32 tokens (2 row-tiles), K=64 (2 slabs), hi+lo
    half8v ah[2][2], al[2][2];
    #pragma unroll
    for (int rt = 0; rt < 2; ++rt) {
        const float* xp = x + (t0w + rt * 16 + l15) * 64 + l4 * 8;
        #pragma unroll
        for (int s = 0; s < 2; ++s) {
            float4 a = *(const float4*)(xp + s * 32);
            float4 b = *(const float4*)(xp + s * 32 + 4);
            cvt8h(a, b, &ah[rt][s], &al[rt][s]);
        }
    }

    float m1[2][4], m2[2][4];
    int i1[2][4], i2[2][4];
    #pragma unroll
    for (int rt = 0; rt < 2; ++rt)
        #pragma unroll
        for (int r = 0; r < 4; ++r) {
            m1[rt][r] = -3.4e38f; m2[rt][r] = -3.4e38f;
            i1[rt][r] = 0; i2[rt][r] = 0;
        }

    for (int ch = 0; ch < 8; ++ch) {
        int c0 = ch * 128;
        // stage 128 codes from pre-split planes: thread -> row r=tid>>1, half h=tid&1
        {
            int r = tid >> 1, h = tid & 1;
            const unsigned short* gh = ewh + (size_t)(c0 + r) * 64 + h * 32;
            const unsigned short* gl = ewl + (size_t)(c0 + r) * 64 + h * 32;
            #pragma unroll
            for (int q = 0; q < 4; ++q) {
                ushort8v hv = *(const ushort8v*)(gh + q * 8);
                ushort8v lv = *(const ushort8v*)(gl + q * 8);
                int byteoff = (r * 128 + h * 64 + q * 16) ^ ((r & 7) << 4);
                *(ushort8v*)((char*)EH + byteoff) = hv;
                *(ushort8v*)((char*)EL + byteoff) = lv;
            }
            if (tid < 128) scc[tid] = cbuf[c0 + tid];
        }
        __syncthreads();

        // zero-fill encodings rows [t0+ch*16, +16): 64KB, overlaps MFMA below
        {
            float2 z; z.x = 0.0f; z.y = 0.0f;
            float* base = out + ENC_OFF + (t0 + (size_t)ch * 16) * 1024;
            #pragma unroll 4
            for (int u = 0; u < 32; ++u) {
                int idx = u * 256 + tid;      // 0..8191
                int row = idx >> 9;
                int c2 = idx & 511;
                *(float2*)(base + (size_t)row * 1024 + c2 * 2) = z;
            }
        }

        #pragma unroll 2
        for (int ct = 0; ct < 8; ++ct) {
            int crow = ct * 16 + l15;
            int swz = (crow & 7) << 4;
            int b0 = (crow * 128 + l4 * 16) ^ swz;
            int b1 = (crow * 128 + 64 + l4 * 16) ^ swz;
            half8v bh0 = *(half8v*)((char*)EH + b0);
            half8v bl0 = *(half8v*)((char*)EL + b0);
            half8v bh1 = *(half8v*)((char*)EH + b1);
            half8v bl1 = *(half8v*)((char*)EL + b1);
            float sccv = scc[crow];
            int cid = c0 + crow;
            #pragma unroll
            for (int rt = 0; rt < 2; ++rt) {
                f32x4 acc = {0.f, 0.f, 0.f, 0.f};
                acc = __builtin_amdgcn_mfma_f32_16x16x32_f16(ah[rt][0], bh0, acc, 0, 0, 0);
                acc = __builtin_amdgcn_mfma_f32_16x16x32_f16(al[rt][0], bh0, acc, 0, 0, 0);
                acc = __builtin_amdgcn_mfma_f32_16x16x32_f16(ah[rt][0], bl0, acc, 0, 0, 0);
                acc = __builtin_amdgcn_mfma_f32_16x16x32_f16(al[rt][0], bl0, acc, 0, 0, 0);
                acc = __builtin_amdgcn_mfma_f32_16x16x32_f16(ah[rt][1], bh1, acc, 0, 0, 0);
                acc = __builtin_amdgcn_mfma_f32_16x16x32_f16(al[rt][1], bh1, acc, 0, 0, 0);
                acc = __builtin_amdgcn_mfma_f32_16x16x32_f16(ah[rt][1], bl1, acc, 0, 0, 0);
                acc = __builtin_amdgcn_mfma_f32_16x16x32_f16(al[rt][1], bl1, acc, 0, 0, 0);
                #pragma unroll
                for (int r = 0; r < 4; ++r) {
                    float sc = acc[r] - sccv;
                    if (sc > m1[rt][r]) {
                        m2[rt][r] = m1[rt][r]; i2[rt][r] = i1[rt][r];
                        m1[rt][r] = sc; i1[rt][r] = cid;
                    } else if (sc > m2[rt][r]) {
                        m2[rt][r] = sc; i2[rt][r] = cid;
                    }
                }
            }
        }
        __syncthreads();
    }

    // merge top-2 across the 16 lanes of each col-group (ties -> lower idx)
    #pragma unroll
    for (int rt = 0; rt < 2; ++rt)
        #pragma unroll
        for (int r = 0; r < 4; ++r) {
            float m1v = m1[rt][r], m2v = m2[rt][r];
            int i1v = i1[rt][r], i2v = i2[rt][r];
            #pragma unroll
            for (int o = 1; o < 16; o <<= 1) {
                float b1 = __shfl_xor(m1v, o, 64); int bi1 = __shfl_xor(i1v, o, 64);
                float b2 = __shfl_xor(m2v, o, 64); int bi2 = __shfl_xor(i2v, o, 64);
                if (b1 > m1v || (b1 == m1v && bi1 < i1v)) {
                    // b1 new top; second = max(old m1, b2)
                    float c2v; int c2i;
                    if (m1v > b2 || (m1v == b2 && i1v < bi2)) { c2v = m1v; c2i = i1v; }
                    else { c2v = b2; c2i = bi2; }
                    m1v = b1; i1v = bi1; m2v = c2v; i2v = c2i;
                } else {
                    if (b1 > m2v || (b1 == m2v && bi1 < i2v)) { m2v = b1; i2v = bi1; }
                }
            }
            if (l15 == 0) {
                size_t tok = t0w + rt * 16 + l4 * 4 + r;
                idxbuf[tok] = (unsigned)i1v;
                if (m2v >= m1v - EPS_SUSPECT) {
                    unsigned p = atomicAdd(suspcnt, 1u);
                    susp[p] = (unsigned)tok;
                }
            }
        }
}

// K1s: exact fp32 re-scan for suspect tokens (bit-identical to the validated r1 arithmetic)
__global__ void k1s_resolve(const float* __restrict__ x, const float* __restrict__ ew,
                            const float* __restrict__ cbuf, const unsigned* __restrict__ susp,
                            const unsigned* __restrict__ suspcnt, unsigned* __restrict__ idxbuf) {
    int lane = threadIdx.x & 63;
    int wid = blockIdx.x * 4 + (threadIdx.x >> 6);   // 256 waves total
    unsigned n = *suspcnt;
    for (unsigned s = wid; s < n; s += 256) {
        unsigned tok = susp[s];
        float4 xr[16];
        const float4* xp = (const float4*)(x + (size_t)tok * 64);
        #pragma unroll
        for (int q = 0; q < 16; ++q) xr[q] = xp[q];
        float best = -3.4e38f;
        int bidx = 0;
        for (int rr = 0; rr < 16; ++rr) {
            int code = rr * 64 + lane;           // per-lane ascending
            const float4* ep = (const float4*)(ew + (size_t)code * 64);
            float d = 0.0f;
            #pragma unroll
            for (int q = 0; q < 16; ++q) {
                float4 xv = xr[q];
                float4 e = ep[q];
                d = fmaf(xv.x, e.x, d); d = fmaf(xv.y, e.y, d);
                d = fmaf(xv.z, e.z, d); d = fmaf(xv.w, e.w, d);
            }
            float sc = d - cbuf[code];
            if (sc > best) { best = sc; bidx = code; }
        }
        #pragma unroll
        for (int o = 1; o < 64; o <<= 1) {
            float vo = __shfl_xor(best, o, 64);
            int io = __shfl_xor(bidx, o, 64);
            if (vo > best || (vo == best && io < bidx)) { best = vo; bidx = io; }
        }
        if (lane == 0) idxbuf[tok] = (unsigned)bidx;
    }
}

// K1h: per-128-token-block LDS histogram + rank -> idxbuf |= rank<<10, blockhist
__global__ void k1h_hist(unsigned* __restrict__ idxbuf, unsigned* __restrict__ blockhist) {
    __shared__ unsigned hist[1024];
    int tid = threadIdx.x;
    #pragma unroll
    for (int q = 0; q < 4; ++q) hist[q * 256 + tid] = 0u;
    __syncthreads();
    if (tid < 128) {
        size_t tok = (size_t)blockIdx.x * 128 + tid;
        unsigned bin = idxbuf[tok];
        unsigned rank = atomicAdd(&hist[bin], 1u);
        idxbuf[tok] = bin | (rank << 10);
    }
    __syncthreads();
    #pragma unroll
    for (int q = 0; q < 4; ++q)
        blockhist[(size_t)blockIdx.x * 1024 + q * 256 + tid] = hist[q * 256 + tid];
}

// K2a: per-bin exclusive scan over 1024 block-histograms (wave per bin) -> blockbase, counts
__global__ void k2a_scan(const unsigned* __restrict__ blockhist,
                         unsigned* __restrict__ blockbase,
                         unsigned* __restrict__ counts) {
    int lane = threadIdx.x & 63;
    int bin = blockIdx.x * 4 + (threadIdx.x >> 6);
    unsigned v[16];
    unsigned s = 0;
    #pragma unroll
    for (int j = 0; j < 16; ++j) v[j] = blockhist[(size_t)(lane * 16 + j) * 1024 + bin];
    #pragma unroll
    for (int j = 0; j < 16; ++j) { unsigned t = v[j]; v[j] = s; s += t; }
    unsigned inc = s;
    for (int o = 1; o < 64; o <<= 1) {
        unsigned n = __shfl_up(inc, o, 64);
        if (lane >= o) inc += n;
    }
    unsigned excl = inc - s;
    #pragma unroll
    for (int j = 0; j < 16; ++j)
        blockbase[(size_t)(lane * 16 + j) * 1024 + bin] = excl + v[j];
    if (lane == 63) counts[bin] = inc;
}

// K2: smoothing, bin offsets, perplexity
__global__ void k2_stats(const float* __restrict__ ema_cs, const unsigned* __restrict__ counts,
                         float* __restrict__ smoothed, unsigned* __restrict__ offsets,
                         float* __restrict__ out) {
    __shared__ unsigned sc[1024];
    __shared__ float sf[1024];
    int t = threadIdx.x;
    unsigned cnt = counts[t];
    float cs = 0.99f * ema_cs[t] + 0.01f * (float)cnt;

    sf[t] = cs; __syncthreads();
    for (int o = 512; o > 0; o >>= 1) { if (t < o) sf[t] += sf[t + o]; __syncthreads(); }
    float n = sf[0];
    __syncthreads();
    smoothed[t] = (cs + 1e-5f) / (n + 1024.0f * 1e-5f) * n;

    sc[t] = cnt; __syncthreads();
    for (int o = 1; o < 1024; o <<= 1) {
        unsigned v = (t >= o) ? sc[t - o] : 0u;
        __syncthreads();
        sc[t] += v;
        __syncthreads();
    }
    offsets[t] = sc[t] - cnt;

    float p = (float)cnt / 131072.0f;
    sf[t] = p * logf(p + 1e-10f); __syncthreads();
    for (int o = 512; o > 0; o >>= 1) { if (t < o) sf[t] += sf[t + o]; __syncthreads(); }
    if (t == 0) out[PERP_OFF] = expf(-sf[0]);
}

// K3: atomic-free scatter (computed position) + one-hot write
__global__ void k3_scatter(const unsigned* __restrict__ idxbuf,
                           const unsigned* __restrict__ offsets,
                           const unsigned* __restrict__ blockbase,
                           int* __restrict__ toklist, int* __restrict__ clustid,
                           float* __restrict__ out) {
    int i = blockIdx.x * 256 + threadIdx.x;
    unsigned v = idxbuf[i];
    unsigned bin = v & 1023u;
    unsigned rank = v >> 10;
    unsigned pos = offsets[bin] + blockbase[(size_t)(i >> 7) * 1024 + bin] + rank;
    toklist[pos] = i;
    clustid[pos] = (int)bin;
    out[ENC_OFF + (size_t)i * 1024 + bin] = 1.0f;
}

// K4a: balanced dw accumulation over sorted positions
__global__ void k4a_dw(const float* __restrict__ x, const int* __restrict__ toklist,
                       const int* __restrict__ clustid, float* __restrict__ dwacc) {
    int lane = threadIdx.x & 63, w = threadIdx.x >> 6;
    int p0 = blockIdx.x * 128 + w * 32;
    int cur = clustid[p0];
    float acc = 0.0f;
    #pragma unroll 4
    for (int t = 0; t < 32; ++t) {
        int pos = p0 + t;
        int c = clustid[pos];
        int tok = toklist[pos];
        float v = x[(size_t)tok * 64 + lane];
        if (c != cur) {
            atomicAdd(&dwacc[(size_t)cur * 64 + lane], acc);
            acc = 0.0f; cur = c;
        }
        acc += v;
    }
    atomicAdd(&dwacc[(size_t)cur * 64 + lane], acc);
}

// K4b: embedding_new = (ema_w*decay + (1-decay)*dw) / smoothed
__global__ void k4b_emb(const float* __restrict__ emaw, const float* __restrict__ dwacc,
                        const float* __restrict__ smoothed, float* __restrict__ embnew) {
    int t = blockIdx.x * 256 + threadIdx.x;
    int k = t >> 6;
    embnew[t] = (emaw[t] * 0.99f + 0.01f * dwacc[t]) / smoothed[k];
}

// K5: quantized output + per-block loss partials (vectorized; 16 tokens/block)
__global__ void k5_output(const float* __restrict__ x, const float* __restrict__ embnew,
                          const unsigned* __restrict__ idxbuf, float* __restrict__ out,
                          float* __restrict__ partials) {
    __shared__ float red[4];
    int tid = threadIdx.x;
    int gid = blockIdx.x * 256 + tid;
    size_t i = (size_t)(gid >> 4);
    int c = (gid & 15) * 4;
    unsigned ii = idxbuf[i] & 1023u;
    float4 xv = *(const float4*)(x + i * 64 + c);
    float4 q = *(const float4*)(embnew + (size_t)ii * 64 + c);
    float* o = out + QUANT_OFF + i * 64 + c;
    float d0 = q.x - xv.x, d1 = q.y - xv.y, d2 = q.z - xv.z, d3 = q.w - xv.w;
    o[0] = xv.x + d0; o[1] = xv.y + d1; o[2] = xv.z + d2; o[3] = xv.w + d3;
    float ls = d0 * d0 + d1 * d1 + d2 * d2 + d3 * d3;
    ls = wave_reduce_sum(ls);
    if ((tid & 63) == 0) red[tid >> 6] = ls;
    __syncthreads();
    if (tid == 0) partials[blockIdx.x] = red[0] + red[1] + red[2] + red[3];
}

// K6: reduce 8192 partials -> loss
__global__ void k6_loss(const float* __restrict__ partials, float* __restrict__ out) {
    __shared__ float red[4];
    int tid = threadIdx.x;   // 256
    float s = 0.0f;
    #pragma unroll 8
    for (int j = 0; j < 32; ++j) s += partials[tid + j * 256];
    s = wave_reduce_sum(s);
    if ((tid & 63) == 0) red[tid >> 6] = s;
    __syncthreads();
    if (tid == 0) out[0] = 0.125f * (red[0] + red[1] + red[2] + red[3]) / 131072.0f;
}

extern "C" void kernel_launch(void* const* d_in, const int* in_sizes, int n_in,
                              void* d_out, int out_size, void* d_ws, size_t ws_size,
                              hipStream_t stream) {
    const float* x     = (const float*)d_in[0];
    const float* ew    = (const float*)d_in[1];
    const float* emaw  = (const float*)d_in[2];
    const float* emacs = (const float*)d_in[3];
    float* out = (float*)d_out;
    float* wsf = (float*)d_ws;

    float*          cbuf      = wsf;                              // 1024
    float*          smoothed  = wsf + 1024;                       // 1024
    unsigned*       offsets   = (unsigned*)(wsf + 2048);          // 1024
    unsigned*       counts    = (unsigned*)(wsf + 3072);          // 1024
    float*          partials  = wsf + 4096;                       // 8192
    unsigned*       suspcnt   = (unsigned*)(wsf + 12288);         // 64 (pad)
    unsigned*       idxbuf    = (unsigned*)(wsf + 12352);         // 131072
    unsigned*       susp      = idxbuf + N_TOK;                   // 131072
    int*            toklist   = (int*)(susp + N_TOK);             // 131072
    int*            clustid   = toklist + N_TOK;                  // 131072
    float*          dwacc     = wsf + 12352 + 4 * N_TOK;          // 65536
    float*          embnew    = dwacc + 65536;                    // 65536
    unsigned*       blockhist = (unsigned*)(embnew + 65536);      // 1024*1024
    unsigned*       blockbase = blockhist + 1024 * 1024;          // 1024*1024
    unsigned short* ewh       = (unsigned short*)(blockbase + 1024 * 1024);  // 65536 u16
    unsigned short* ewl       = ewh + 65536;                      // 65536 u16

    hipLaunchKernelGGL(k0_prep,    dim3(32),   dim3(256),  0, stream, ew, cbuf, ewh, ewl, dwacc, suspcnt);
    hipLaunchKernelGGL(k1_argmin,  dim3(1024), dim3(256),  0, stream, x, ewh, ewl, cbuf, out, idxbuf, susp, suspcnt);
    hipLaunchKernelGGL(k1s_resolve,dim3(64),   dim3(256),  0, stream, x, ew, cbuf, susp, suspcnt, idxbuf);
    hipLaunchKernelGGL(k1h_hist,   dim3(1024), dim3(256),  0, stream, idxbuf, blockhist);
    hipLaunchKernelGGL(k2a_scan,   dim3(256),  dim3(256),  0, stream, blockhist, blockbase, counts);
    hipLaunchKernelGGL(k2_stats,   dim3(1),    dim3(1024), 0, stream, emacs, counts, smoothed, offsets, out);
    hipLaunchKernelGGL(k3_scatter, dim3(512),  dim3(256),  0, stream, idxbuf, offsets, blockbase, toklist, clustid, out);
    hipLaunchKernelGGL(k4a_dw,     dim3(1024), dim3(256),  0, stream, x, toklist, clustid, dwacc);
    hipLaunchKernelGGL(k4b_emb,    dim3(256),  dim3(256),  0, stream, emaw, dwacc, smoothed, embnew);
    hipLaunchKernelGGL(k5_output,  dim3(8192), dim3(256),  0, stream, x, embnew, idxbuf, out, partials);
    hipLaunchKernelGGL(k6_loss,    dim3(1),    dim3(256),  0, stream, partials, out);
}

// Round 7
// 731.536 us; speedup vs baseline: 1.0037x; 1.0037x over previous
//
#include <hip/hip_runtime.h>
#include <hip/hip_fp16.h>

#define N_TOK 131072
#define KCODES 1024
#define DIM 64
#define QUANT_OFF 1
#define PERP_OFF 8388609
#define ENC_OFF ((size_t)8388610)
#define EPS_SUSPECT 4e-3f

typedef __attribute__((ext_vector_type(8))) unsigned short ushort8v;
typedef __attribute__((ext_vector_type(8))) _Float16 half8v;
typedef __attribute__((ext_vector_type(4))) float f32x4;

__device__ __forceinline__ float wave_reduce_sum(float v) {
    #pragma unroll
    for (int o = 32; o > 0; o >>= 1) v += __shfl_xor(v, o, 64);
    return v;
}

// split 8 fp32 -> fp16 hi + fp16 lo (f ~= hi + lo to ~2^-23 rel)
__device__ __forceinline__ void cvt8h(const float4 a, const float4 b,
                                      half8v* h, half8v* l) {
    float f[8] = {a.x, a.y, a.z, a.w, b.x, b.y, b.z, b.w};
    #pragma unroll
    for (int j = 0; j < 8; ++j) {
        _Float16 hh = (_Float16)f[j];
        float fh = (float)hh;
        _Float16 ll = (_Float16)(f[j] - fh);
        (*h)[j] = hh;
        (*l)[j] = ll;
    }
}

// K0: cbuf[j]=0.5*||e_j||^2 (exact fp32); fp16 split planes; zero dwacc+suspcnt
__global__ void k0_prep(const float* __restrict__ ew, float* __restrict__ cbuf,
                        unsigned short* __restrict__ ewh, unsigned short* __restrict__ ewl,
                        float* __restrict__ dwacc, unsigned* __restrict__ suspcnt) {
    int tid = threadIdx.x;
    int lane = tid & 63;
    int wg = blockIdx.x * 4 + (tid >> 6);   // 128 waves
    int gt = blockIdx.x * 256 + tid;        // 8192 threads
    if (gt == 0) *suspcnt = 0u;
    #pragma unroll
    for (int z = 0; z < 8; ++z) {
        int e = gt * 8 + z;
        float v = ew[e];
        _Float16 hh = (_Float16)v;
        float fh = (float)hh;
        _Float16 ll = (_Float16)(v - fh);
        unsigned short uh, ul;
        __builtin_memcpy(&uh, &hh, 2);
        __builtin_memcpy(&ul, &ll, 2);
        ewh[e] = uh;
        ewl[e] = ul;
        dwacc[e] = 0.0f;
    }
    #pragma unroll
    for (int k = 0; k < 8; ++k) {
        int row = wg * 8 + k;
        float v = ew[row * 64 + lane];
        float s = wave_reduce_sum(v * v);
        if (lane == 0) cbuf[row] = 0.5f * s;
    }
}

// K1: MFMA argmin filter (fp16 split, 3 terms) + top-2 + suspect list + float4 zero-fill.
// 1024 blocks x 256 thr; block = 128 tokens (4 waves x 32), codes in 8 chunks of 128.
__global__ __launch_bounds__(256) void k1_argmin(
        const float* __restrict__ x, const unsigned short* __restrict__ ewh,
        const unsigned short* __restrict__ ewl, const float* __restrict__ cbuf,
        float* __restrict__ out, unsigned* __restrict__ idxbuf,
        unsigned* __restrict__ susp, unsigned* __restrict__ suspcnt) {
    __shared__ unsigned short EH[128 * 64];   // fp16 hi, XOR-swizzled rows
    __shared__ unsigned short EL[128 * 64];   // fp16 lo
    __shared__ float scc[128];

    int tid = threadIdx.x;
    int lane = tid & 63;
    int wv = tid >> 6;
    int l15 = lane & 15;
    int l4 = lane >> 4;
    size_t t0 = (size_t)blockIdx.x * 128;
    size_t t0w = t0 + (size_t)wv * 32;

    // A fragments: wave's 32 tokens (2 row-tiles), K=64 (2 slabs), hi+lo
    half8v ah[2][2], al[2][2];
    #pragma unroll
    for (int rt = 0; rt < 2; ++rt) {
        const float* xp = x + (t0w + rt * 16 + l15) * 64 + l4 * 8;
        #pragma unroll
        for (int s = 0; s < 2; ++s) {
            float4 a = *(const float4*)(xp + s * 32);
            float4 b = *(const float4*)(xp + s * 32 + 4);
            cvt8h(a, b, &ah[rt][s], &al[rt][s]);
        }
    }

    float m1[2][4], m2[2][4];
    int i1[2][4], i2[2][4];
    #pragma unroll
    for (int rt = 0; rt < 2; ++rt)
        #pragma unroll
        for (int r = 0; r < 4; ++r) {
            m1[rt][r] = -3.4e38f; m2[rt][r] = -3.4e38f;
            i1[rt][r] = 0; i2[rt][r] = 0;
        }

    for (int ch = 0; ch < 8; ++ch) {
        int c0 = ch * 128;
        // stage 128 codes from pre-split planes: thread -> row r=tid>>1, half h=tid&1
        {
            int r = tid >> 1, h = tid & 1;
            const unsigned short* gh = ewh + (size_t)(c0 + r) * 64 + h * 32;
            const unsigned short* gl = ewl + (size_t)(c0 + r) * 64 + h * 32;
            #pragma unroll
            for (int q = 0; q < 4; ++q) {
                ushort8v hv = *(const ushort8v*)(gh + q * 8);
                ushort8v lv = *(const ushort8v*)(gl + q * 8);
                int byteoff = (r * 128 + h * 64 + q * 16) ^ ((r & 7) << 4);
                *(ushort8v*)((char*)EH + byteoff) = hv;
                *(ushort8v*)((char*)EL + byteoff) = lv;
            }
            if (tid < 128) scc[tid] = cbuf[c0 + tid];
        }
        __syncthreads();

        // zero-fill encodings rows [t0+ch*16, +16): one contiguous 64KB span,
        // base byte == 8 (mod 16): head/tail float2 + 4095 aligned float4.
        {
            float* base = out + ENC_OFF + (t0 + (size_t)ch * 16) * 1024;
            float4 z4; z4.x = z4.y = z4.z = z4.w = 0.0f;
            float2 z2; z2.x = z2.y = 0.0f;
            float4* b4 = (float4*)(base + 2);
            #pragma unroll 4
            for (int u = 0; u < 16; ++u) {
                int slot = u * 256 + tid;
                if (slot < 4095) b4[slot] = z4;
            }
            if (tid == 0) *(float2*)base = z2;
            if (tid == 255) *(float2*)(base + 16382) = z2;
        }

        #pragma unroll 2
        for (int ct = 0; ct < 8; ++ct) {
            int crow = ct * 16 + l15;
            int swz = (crow & 7) << 4;
            int b0 = (crow * 128 + l4 * 16) ^ swz;
            int b1 = (crow * 128 + 64 + l4 * 16) ^ swz;
            half8v bh0 = *(half8v*)((char*)EH + b0);
            half8v bl0 = *(half8v*)((char*)EL + b0);
            half8v bh1 = *(half8v*)((char*)EH + b1);
            half8v bl1 = *(half8v*)((char*)EL + b1);
            float sccv = scc[crow];
            int cid = c0 + crow;
            #pragma unroll
            for (int rt = 0; rt < 2; ++rt) {
                f32x4 acc = {0.f, 0.f, 0.f, 0.f};
                acc = __builtin_amdgcn_mfma_f32_16x16x32_f16(ah[rt][0], bh0, acc, 0, 0, 0);
                acc = __builtin_amdgcn_mfma_f32_16x16x32_f16(al[rt][0], bh0, acc, 0, 0, 0);
                acc = __builtin_amdgcn_mfma_f32_16x16x32_f16(ah[rt][0], bl0, acc, 0, 0, 0);
                acc = __builtin_amdgcn_mfma_f32_16x16x32_f16(ah[rt][1], bh1, acc, 0, 0, 0);
                acc = __builtin_amdgcn_mfma_f32_16x16x32_f16(al[rt][1], bh1, acc, 0, 0, 0);
                acc = __builtin_amdgcn_mfma_f32_16x16x32_f16(ah[rt][1], bl1, acc, 0, 0, 0);
                #pragma unroll
                for (int r = 0; r < 4; ++r) {
                    float sc = acc[r] - sccv;
                    if (sc > m1[rt][r]) {
                        m2[rt][r] = m1[rt][r]; i2[rt][r] = i1[rt][r];
                        m1[rt][r] = sc; i1[rt][r] = cid;
                    } else if (sc > m2[rt][r]) {
                        m2[rt][r] = sc; i2[rt][r] = cid;
                    }
                }
            }
        }
        __syncthreads();
    }

    // merge top-2 across the 16 lanes of each col-group (ties -> lower idx)
    #pragma unroll
    for (int rt = 0; rt < 2; ++rt)
        #pragma unroll
        for (int r = 0; r < 4; ++r) {
            float m1v = m1[rt][r], m2v = m2[rt][r];
            int i1v = i1[rt][r], i2v = i2[rt][r];
            #pragma unroll
            for (int o = 1; o < 16; o <<= 1) {
                float b1 = __shfl_xor(m1v, o, 64); int bi1 = __shfl_xor(i1v, o, 64);
                float b2 = __shfl_xor(m2v, o, 64); int bi2 = __shfl_xor(i2v, o, 64);
                if (b1 > m1v || (b1 == m1v && bi1 < i1v)) {
                    float c2v; int c2i;
                    if (m1v > b2 || (m1v == b2 && i1v < bi2)) { c2v = m1v; c2i = i1v; }
                    else { c2v = b2; c2i = bi2; }
                    m1v = b1; i1v = bi1; m2v = c2v; i2v = c2i;
                } else {
                    if (b1 > m2v || (b1 == m2v && bi1 < i2v)) { m2v = b1; i2v = bi1; }
                }
            }
            if (l15 == 0) {
                size_t tok = t0w + rt * 16 + l4 * 4 + r;
                idxbuf[tok] = (unsigned)i1v;
                if (m2v >= m1v - EPS_SUSPECT) {
                    unsigned p = atomicAdd(suspcnt, 1u);
                    susp[p] = (unsigned)tok;
                }
            }
        }
}

// K1s: exact fp32 re-scan for suspect tokens (bit-identical to the validated r1 arithmetic)
__global__ void k1s_resolve(const float* __restrict__ x, const float* __restrict__ ew,
                            const float* __restrict__ cbuf, const unsigned* __restrict__ susp,
                            const unsigned* __restrict__ suspcnt, unsigned* __restrict__ idxbuf) {
    int lane = threadIdx.x & 63;
    int wid = blockIdx.x * 4 + (threadIdx.x >> 6);   // 256 waves total
    unsigned n = *suspcnt;
    for (unsigned s = wid; s < n; s += 256) {
        unsigned tok = susp[s];
        float4 xr[16];
        const float4* xp = (const float4*)(x + (size_t)tok * 64);
        #pragma unroll
        for (int q = 0; q < 16; ++q) xr[q] = xp[q];
        float best = -3.4e38f;
        int bidx = 0;
        for (int rr = 0; rr < 16; ++rr) {
            int code = rr * 64 + lane;
            const float4* ep = (const float4*)(ew + (size_t)code * 64);
            float d = 0.0f;
            #pragma unroll
            for (int q = 0; q < 16; ++q) {
                float4 xv = xr[q];
                float4 e = ep[q];
                d = fmaf(xv.x, e.x, d); d = fmaf(xv.y, e.y, d);
                d = fmaf(xv.z, e.z, d); d = fmaf(xv.w, e.w, d);
            }
            float sc = d - cbuf[code];
            if (sc > best) { best = sc; bidx = code; }
        }
        #pragma unroll
        for (int o = 1; o < 64; o <<= 1) {
            float vo = __shfl_xor(best, o, 64);
            int io = __shfl_xor(bidx, o, 64);
            if (vo > best || (vo == best && io < bidx)) { best = vo; bidx = io; }
        }
        if (lane == 0) idxbuf[tok] = (unsigned)bidx;
    }
}

// K1h: per-128-token-block LDS histogram + rank -> idxbuf |= rank<<10, blockhist
__global__ void k1h_hist(unsigned* __restrict__ idxbuf, unsigned* __restrict__ blockhist) {
    __shared__ unsigned hist[1024];
    int tid = threadIdx.x;
    #pragma unroll
    for (int q = 0; q < 4; ++q) hist[q * 256 + tid] = 0u;
    __syncthreads();
    if (tid < 128) {
        size_t tok = (size_t)blockIdx.x * 128 + tid;
        unsigned bin = idxbuf[tok];
        unsigned rank = atomicAdd(&hist[bin], 1u);
        idxbuf[tok] = bin | (rank << 10);
    }
    __syncthreads();
    #pragma unroll
    for (int q = 0; q < 4; ++q)
        blockhist[(size_t)blockIdx.x * 1024 + q * 256 + tid] = hist[q * 256 + tid];
}

// K2a: per-bin exclusive scan over 1024 block-histograms (wave per bin) -> blockbase, counts
__global__ void k2a_scan(const unsigned* __restrict__ blockhist,
                         unsigned* __restrict__ blockbase,
                         unsigned* __restrict__ counts) {
    int lane = threadIdx.x & 63;
    int bin = blockIdx.x * 4 + (threadIdx.x >> 6);
    unsigned v[16];
    unsigned s = 0;
    #pragma unroll
    for (int j = 0; j < 16; ++j) v[j] = blockhist[(size_t)(lane * 16 + j) * 1024 + bin];
    #pragma unroll
    for (int j = 0; j < 16; ++j) { unsigned t = v[j]; v[j] = s; s += t; }
    unsigned inc = s;
    for (int o = 1; o < 64; o <<= 1) {
        unsigned n = __shfl_up(inc, o, 64);
        if (lane >= o) inc += n;
    }
    unsigned excl = inc - s;
    #pragma unroll
    for (int j = 0; j < 16; ++j)
        blockbase[(size_t)(lane * 16 + j) * 1024 + bin] = excl + v[j];
    if (lane == 63) counts[bin] = inc;
}

// K2: smoothing, bin offsets, perplexity (wave-shuffle scans, 4 barriers)
__global__ void k2_stats(const float* __restrict__ ema_cs, const unsigned* __restrict__ counts,
                         float* __restrict__ smoothed, unsigned* __restrict__ offsets,
                         float* __restrict__ out) {
    __shared__ float sfw[16];
    __shared__ unsigned scw[16];
    __shared__ float nsh;
    int t = threadIdx.x;
    int lane = t & 63, w = t >> 6;
    unsigned cnt = counts[t];
    float cs = 0.99f * ema_cs[t] + 0.01f * (float)cnt;

    float s = wave_reduce_sum(cs);
    if (lane == 0) sfw[w] = s;
    __syncthreads();
    if (t == 0) {
        float n = 0.f;
        #pragma unroll
        for (int j = 0; j < 16; ++j) n += sfw[j];
        nsh = n;
    }
    __syncthreads();
    float n = nsh;
    smoothed[t] = (cs + 1e-5f) / (n + 1024.0f * 1e-5f) * n;

    unsigned inc = cnt;
    #pragma unroll
    for (int o = 1; o < 64; o <<= 1) {
        unsigned v = __shfl_up(inc, o, 64);
        if (lane >= o) inc += v;
    }
    if (lane == 63) scw[w] = inc;
    __syncthreads();
    unsigned wb = 0;
    #pragma unroll
    for (int j = 0; j < 16; ++j) if (j < w) wb += scw[j];
    offsets[t] = wb + inc - cnt;

    float p = (float)cnt / 131072.0f;
    float term = p * logf(p + 1e-10f);
    float ps = wave_reduce_sum(term);
    if (lane == 0) sfw[w] = ps;
    __syncthreads();
    if (t == 0) {
        float e = 0.f;
        #pragma unroll
        for (int j = 0; j < 16; ++j) e += sfw[j];
        out[PERP_OFF] = expf(-e);
    }
}

// K3: atomic-free scatter (computed position) + one-hot write
__global__ void k3_scatter(const unsigned* __restrict__ idxbuf,
                           const unsigned* __restrict__ offsets,
                           const unsigned* __restrict__ blockbase,
                           int* __restrict__ toklist, int* __restrict__ clustid,
                           float* __restrict__ out) {
    int i = blockIdx.x * 256 + threadIdx.x;
    unsigned v = idxbuf[i];
    unsigned bin = v & 1023u;
    unsigned rank = v >> 10;
    unsigned pos = offsets[bin] + blockbase[(size_t)(i >> 7) * 1024 + bin] + rank;
    toklist[pos] = i;
    clustid[pos] = (int)bin;
    out[ENC_OFF + (size_t)i * 1024 + bin] = 1.0f;
}

// K4a: balanced dw accumulation over sorted positions
__global__ void k4a_dw(const float* __restrict__ x, const int* __restrict__ toklist,
                       const int* __restrict__ clustid, float* __restrict__ dwacc) {
    int lane = threadIdx.x & 63, w = threadIdx.x >> 6;
    int p0 = blockIdx.x * 128 + w * 32;
    int cur = clustid[p0];
    float acc = 0.0f;
    #pragma unroll 4
    for (int t = 0; t < 32; ++t) {
        int pos = p0 + t;
        int c = clustid[pos];
        int tok = toklist[pos];
        float v = x[(size_t)tok * 64 + lane];
        if (c != cur) {
            atomicAdd(&dwacc[(size_t)cur * 64 + lane], acc);
            acc = 0.0f; cur = c;
        }
        acc += v;
    }
    atomicAdd(&dwacc[(size_t)cur * 64 + lane], acc);
}

// K4b: embedding_new = (ema_w*decay + (1-decay)*dw) / smoothed
__global__ void k4b_emb(const float* __restrict__ emaw, const float* __restrict__ dwacc,
                        const float* __restrict__ smoothed, float* __restrict__ embnew) {
    int t = blockIdx.x * 256 + threadIdx.x;
    int k = t >> 6;
    embnew[t] = (emaw[t] * 0.99f + 0.01f * dwacc[t]) / smoothed[k];
}

// K5: quantized output + per-block loss partials (vectorized; 16 tokens/block)
__global__ void k5_output(const float* __restrict__ x, const float* __restrict__ embnew,
                          const unsigned* __restrict__ idxbuf, float* __restrict__ out,
                          float* __restrict__ partials) {
    __shared__ float red[4];
    int tid = threadIdx.x;
    int gid = blockIdx.x * 256 + tid;
    size_t i = (size_t)(gid >> 4);
    int c = (gid & 15) * 4;
    unsigned ii = idxbuf[i] & 1023u;
    float4 xv = *(const float4*)(x + i * 64 + c);
    float4 q = *(const float4*)(embnew + (size_t)ii * 64 + c);
    float* o = out + QUANT_OFF + i * 64 + c;
    float d0 = q.x - xv.x, d1 = q.y - xv.y, d2 = q.z - xv.z, d3 = q.w - xv.w;
    o[0] = xv.x + d0; o[1] = xv.y + d1; o[2] = xv.z + d2; o[3] = xv.w + d3;
    float ls = d0 * d0 + d1 * d1 + d2 * d2 + d3 * d3;
    ls = wave_reduce_sum(ls);
    if ((tid & 63) == 0) red[tid >> 6] = ls;
    __syncthreads();
    if (tid == 0) partials[blockIdx.x] = red[0] + red[1] + red[2] + red[3];
}

// K6: reduce 8192 partials -> loss
__global__ void k6_loss(const float* __restrict__ partials, float* __restrict__ out) {
    __shared__ float red[4];
    int tid = threadIdx.x;   // 256
    float s = 0.0f;
    #pragma unroll 8
    for (int j = 0; j < 32; ++j) s += partials[tid + j * 256];
    s = wave_reduce_sum(s);
    if ((tid & 63) == 0) red[tid >> 6] = s;
    __syncthreads();
    if (tid == 0) out[0] = 0.125f * (red[0] + red[1] + red[2] + red[3]) / 131072.0f;
}

extern "C" void kernel_launch(void* const* d_in, const int* in_sizes, int n_in,
                              void* d_out, int out_size, void* d_ws, size_t ws_size,
                              hipStream_t stream) {
    const float* x     = (const float*)d_in[0];
    const float* ew    = (const float*)d_in[1];
    const float* emaw  = (const float*)d_in[2];
    const float* emacs = (const float*)d_in[3];
    float* out = (float*)d_out;
    float* wsf = (float*)d_ws;

    float*          cbuf      = wsf;                              // 1024
    float*          smoothed  = wsf + 1024;                       // 1024
    unsigned*       offsets   = (unsigned*)(wsf + 2048);          // 1024
    unsigned*       counts    = (unsigned*)(wsf + 3072);          // 1024
    float*          partials  = wsf + 4096;                       // 8192
    unsigned*       suspcnt   = (unsigned*)(wsf + 12288);         // 64 (pad)
    unsigned*       idxbuf    = (unsigned*)(wsf + 12352);         // 131072
    unsigned*       susp      = idxbuf + N_TOK;                   // 131072
    int*            toklist   = (int*)(susp + N_TOK);             // 131072
    int*            clustid   = toklist + N_TOK;                  // 131072
    float*          dwacc     = wsf + 12352 + 4 * N_TOK;          // 65536
    float*          embnew    = dwacc + 65536;                    // 65536
    unsigned*       blockhist = (unsigned*)(embnew + 65536);      // 1024*1024
    unsigned*       blockbase = blockhist + 1024 * 1024;          // 1024*1024
    unsigned short* ewh       = (unsigned short*)(blockbase + 1024 * 1024);  // 65536 u16
    unsigned short* ewl       = ewh + 65536;                      // 65536 u16

    hipLaunchKernelGGL(k0_prep,    dim3(32),   dim3(256),  0, stream, ew, cbuf, ewh, ewl, dwacc, suspcnt);
    hipLaunchKernelGGL(k1_argmin,  dim3(1024), dim3(256),  0, stream, x, ewh, ewl, cbuf, out, idxbuf, susp, suspcnt);
    hipLaunchKernelGGL(k1s_resolve,dim3(64),   dim3(256),  0, stream, x, ew, cbuf, susp, suspcnt, idxbuf);
    hipLaunchKernelGGL(k1h_hist,   dim3(1024), dim3(256),  0, stream, idxbuf, blockhist);
    hipLaunchKernelGGL(k2a_scan,   dim3(256),  dim3(256),  0, stream, blockhist, blockbase, counts);
    hipLaunchKernelGGL(k2_stats,   dim3(1),    dim3(1024), 0, stream, emacs, counts, smoothed, offsets, out);
    hipLaunchKernelGGL(k3_scatter, dim3(512),  dim3(256),  0, stream, idxbuf, offsets, blockbase, toklist, clustid, out);
    hipLaunchKernelGGL(k4a_dw,     dim3(1024), dim3(256),  0, stream, x, toklist, clustid, dwacc);
    hipLaunchKernelGGL(k4b_emb,    dim3(256),  dim3(256),  0, stream, emaw, dwacc, smoothed, embnew);
    hipLaunchKernelGGL(k5_output,  dim3(8192), dim3(256),  0, stream, x, embnew, idxbuf, out, partials);
    hipLaunchKernelGGL(k6_loss,    dim3(1),    dim3(256),  0, stream, partials, out);
}